// Round 1
// baseline (249.419 us; speedup 1.0000x reference)
//
#include <hip/hip_runtime.h>

// MPS tensor-train classifier, B=16384, D=784, BOND=5, OUT=10.
//
// res[b] = carry0(x[b,0]) . (prod_{d=1..782} M_d(x[b,d])) . vlast(x[b,783])
// M_d = (1-x)*A0_d + x*A1_d, A0/A1 are 5x5 slices of cores_mid[d-1].
//
// Split at the midpoint: wave 0 of each block computes the forward half
// (row-vector chain, sites d=1..391), wave 1 the backward half (column-vector
// chain, sites d=782..392) for the same 64 batch rows. Combine via LDS.
// 256 blocks x 128 threads = 512 waves (2 per CU).

constexpr int Bn   = 16384;
constexpr int Dn   = 784;
constexpr int BOND = 5;
constexpr int NOUT = 10;

// forward site step: c <- c @ M  (row vector times matrix)
__device__ __forceinline__ void fstep(float c[BOND], float xv,
                                      const float* __restrict__ cm) {
    float v0[BOND], v1[BOND];
#pragma unroll
    for (int r = 0; r < BOND; ++r) { v0[r] = 0.0f; v1[r] = 0.0f; }
#pragma unroll
    for (int l = 0; l < BOND; ++l) {
        const float cl = c[l];
#pragma unroll
        for (int r = 0; r < BOND; ++r) {
            v0[r] = fmaf(cl, cm[l * 10 + r],     v0[r]);
            v1[r] = fmaf(cl, cm[l * 10 + 5 + r], v1[r]);
        }
    }
#pragma unroll
    for (int r = 0; r < BOND; ++r) c[r] = fmaf(xv, v1[r] - v0[r], v0[r]);
}

// backward site step: c <- M @ c  (matrix times column vector)
__device__ __forceinline__ void bstep(float c[BOND], float xv,
                                      const float* __restrict__ cm) {
    float v0[BOND], v1[BOND];
#pragma unroll
    for (int l = 0; l < BOND; ++l) { v0[l] = 0.0f; v1[l] = 0.0f; }
#pragma unroll
    for (int r = 0; r < BOND; ++r) {
        const float rr = c[r];
#pragma unroll
        for (int l = 0; l < BOND; ++l) {
            v0[l] = fmaf(rr, cm[l * 10 + r],     v0[l]);
            v1[l] = fmaf(rr, cm[l * 10 + 5 + r], v1[l]);
        }
    }
#pragma unroll
    for (int l = 0; l < BOND; ++l) c[l] = fmaf(xv, v1[l] - v0[l], v0[l]);
}

__global__ __launch_bounds__(128)
void mps_fwd_bwd_kernel(const float* __restrict__ x,          // [B, D]
                        const float* __restrict__ core_first, // [2,5]
                        const float* __restrict__ cores_mid,  // [782,5,2,5]
                        const float* __restrict__ core_last,  // [5,2]
                        const float* __restrict__ fc_w,       // [10]
                        const float* __restrict__ fc_b,       // [10]
                        float* __restrict__ out)              // [B,10]
{
    __shared__ float bv_s[64][BOND];  // backward vectors, one per batch row

    const int lane = threadIdx.x & 63;
    const int wave = threadIdx.x >> 6;
    const int b    = blockIdx.x * 64 + lane;

    const float4* xrow4 = (const float4*)(x + (size_t)b * Dn);  // 196 chunks

    float c[BOND];

    if (wave == 0) {
        // ---- forward half: sites d = 0 (init) then 1..391 (m = 0..390) ----
        float4 xc = xrow4[0];                 // x[b, 0..3]
        const float x0 = xc.x;
#pragma unroll
        for (int r = 0; r < BOND; ++r)
            c[r] = fmaf(x0, core_first[5 + r] - core_first[r], core_first[r]);
        fstep(c, xc.y, cores_mid + 0 * 50);   // d=1, m=0
        fstep(c, xc.z, cores_mid + 1 * 50);
        fstep(c, xc.w, cores_mid + 2 * 50);
        for (int j = 1; j < 98; ++j) {
            xc = xrow4[j];                    // x[b, 4j .. 4j+3]
            const float* cmp = cores_mid + (size_t)(4 * j - 1) * 50;
            fstep(c, xc.x, cmp);              // d=4j,   m=4j-1
            fstep(c, xc.y, cmp + 50);
            fstep(c, xc.z, cmp + 100);
            fstep(c, xc.w, cmp + 150);        // d=4j+3, m=4j+2 (last: m=390)
        }
        __syncthreads();
        // combine with backward vector, write output row
        float res = 0.0f;
#pragma unroll
        for (int l = 0; l < BOND; ++l) res = fmaf(c[l], bv_s[lane][l], res);
        float* orow = out + (size_t)b * NOUT;
#pragma unroll
        for (int o = 0; o < NOUT; ++o) orow[o] = fmaf(res, fc_w[o], fc_b[o]);
    } else {
        // ---- backward half: site 783 (init) then d = 782..392 (m=781..391) ----
        float4 xc = xrow4[195];               // x[b, 780..783]
        const float xl = xc.w;
#pragma unroll
        for (int l = 0; l < BOND; ++l)
            c[l] = fmaf(xl, core_last[l * 2 + 1] - core_last[l * 2],
                        core_last[l * 2]);
        bstep(c, xc.z, cores_mid + (size_t)781 * 50);  // d=782, m=781
        bstep(c, xc.y, cores_mid + (size_t)780 * 50);
        bstep(c, xc.x, cores_mid + (size_t)779 * 50);
        for (int j = 194; j >= 98; --j) {
            xc = xrow4[j];                    // x[b, 4j .. 4j+3]
            const float* cmp = cores_mid + (size_t)(4 * j - 1) * 50;
            bstep(c, xc.w, cmp + 150);        // d=4j+3, m=4j+2
            bstep(c, xc.z, cmp + 100);
            bstep(c, xc.y, cmp + 50);
            bstep(c, xc.x, cmp);              // d=4j,   m=4j-1 (last: m=391)
        }
#pragma unroll
        for (int l = 0; l < BOND; ++l) bv_s[lane][l] = c[l];
        __syncthreads();
    }
}

extern "C" void kernel_launch(void* const* d_in, const int* in_sizes, int n_in,
                              void* d_out, int out_size, void* d_ws, size_t ws_size,
                              hipStream_t stream) {
    const float* x          = (const float*)d_in[0];
    const float* core_first = (const float*)d_in[1];
    const float* cores_mid  = (const float*)d_in[2];
    const float* core_last  = (const float*)d_in[3];
    const float* fc_w       = (const float*)d_in[4];
    const float* fc_b       = (const float*)d_in[5];
    float* out              = (float*)d_out;

    dim3 grid(Bn / 64);   // 256 blocks
    dim3 block(128);      // 2 waves: forward + backward
    hipLaunchKernelGGL(mps_fwd_bwd_kernel, grid, block, 0, stream,
                       x, core_first, cores_mid, core_last, fc_w, fc_b, out);
}

// Round 2
// 173.745 us; speedup vs baseline: 1.4355x; 1.4355x over previous
//
#include <hip/hip_runtime.h>

// MPS tensor-train classifier, B=16384, D=784, BOND=5, OUT=10.
//
// res[b] = carry0(x[b,0]) . (prod_{m=0..781} M_m(x[b,m+1])) . vlast(x[b,783])
// M_m = A0_m + x * N_m, with N = A1 - A0 (prepacked into d_ws).
//
// Round-2 structure: 256 blocks x 1024 threads (16 waves). Each block owns 64
// batch rows (row = blockIdx*64 + lane). Chain split into 16 segments:
//   wave 0   : forward row-vector chain, sites m = 0..110          (111 sites)
//   waves 1-14: 5x5 matrix-product segments, 40 sites each, m = 111..670
//   wave 15  : backward column-vector chain, sites m = 781..671    (111 sites)
// Segment results combined in-block via LDS in two phases (7 matrices at a
// time -> 44.8 KB, fits static shared). Balanced: 111*57 ~= 40*151 instrs.
// 4096 waves total = 4 waves/SIMD on all SIMDs (round 1 had 1 wave/SIMD on
// half the SIMDs -> 90% latency stall).

constexpr int Bn   = 16384;
constexpr int Dn   = 784;
constexpr int NMID = Dn - 2;   // 782 middle sites
constexpr int PKW  = 64;       // padded floats per prepacked site (256 B, aligned)
constexpr int NVEC = 111;      // sites per vector wave
constexpr int NMAT = 40;       // sites per matrix wave; 14*40 + 2*111 = 782
constexpr int NOUT = 10;

// ---- prepack: pk[m][10*l + j] = (j<5) ? A0[m][l][j] : A1[m][l][j-5]-A0[m][l][j-5]
// cores_mid element (m,l,i,r) at ((m*5+l)*2+i)*5+r
__global__ void prepack_kernel(const float* __restrict__ cm, float* __restrict__ pk)
{
    int idx = blockIdx.x * 256 + threadIdx.x;
    if (idx >= NMID * 50) return;
    int m = idx / 50, k = idx - m * 50;
    int l = k / 10, j = k - l * 10;
    const float* base = cm + (size_t)(m * 5 + l) * 10;  // [i=0..1][r=0..4]
    float v;
    if (j < 5) v = base[j];
    else       v = base[5 + (j - 5)] - base[j - 5];
    pk[(size_t)m * PKW + k] = v;
}

// one matrix site step: T = M @ (A0 + x*N), fully unrolled, 150 VALU
__device__ __forceinline__ void mstep(const float M[25], float T[25],
                                      const float* __restrict__ s, float xv)
{
    float md[5];
#pragma unroll
    for (int r = 0; r < 5; ++r) md[r] = fmaf(xv, s[5 + r], s[r]);     // row l=0
#pragma unroll
    for (int i = 0; i < 5; ++i)
#pragma unroll
        for (int r = 0; r < 5; ++r) T[i * 5 + r] = M[i * 5] * md[r];
#pragma unroll
    for (int l = 1; l < 5; ++l) {
#pragma unroll
        for (int r = 0; r < 5; ++r) md[r] = fmaf(xv, s[10 * l + 5 + r], s[10 * l + r]);
#pragma unroll
        for (int i = 0; i < 5; ++i)
#pragma unroll
            for (int r = 0; r < 5; ++r)
                T[i * 5 + r] = fmaf(M[i * 5 + l], md[r], T[i * 5 + r]);
    }
}

__global__ __launch_bounds__(1024)
void mps_seg_kernel(const float* __restrict__ x,          // [B, D]
                    const float* __restrict__ core_first, // [2,5]
                    const float* __restrict__ core_last,  // [5,2]
                    const float* __restrict__ fc_w,       // [10]
                    const float* __restrict__ fc_b,       // [10]
                    const float* __restrict__ pk,         // [782][64] prepacked
                    float* __restrict__ out)              // [B,10]
{
    __shared__ float matbuf[7][25][64];   // [slot][k=l*5+r][lane] 44.8 KB
    __shared__ float bv[5][64];           // backward vectors

    const int lane = threadIdx.x & 63;
    const int wave = threadIdx.x >> 6;
    const int row  = blockIdx.x * 64 + lane;
    const float* __restrict__ xr = x + (size_t)row * Dn;

    if (wave == 0) {
        // ---- forward vector segment: d=0 init, then m = 0..NVEC-1 ----
        float c[5];
        const float x0 = xr[0];
#pragma unroll
        for (int r = 0; r < 5; ++r)
            c[r] = fmaf(x0, core_first[5 + r] - core_first[r], core_first[r]);
        float xv = xr[1];
        for (int m = 0; m < NVEC; ++m) {
            const float* s = pk + (size_t)m * PKW;
            const float xn = xr[m + 2];            // prefetch next site's x
            float v0[5], t[5];
#pragma unroll
            for (int r = 0; r < 5; ++r) { v0[r] = c[0] * s[r]; t[r] = c[0] * s[5 + r]; }
#pragma unroll
            for (int l = 1; l < 5; ++l)
#pragma unroll
                for (int r = 0; r < 5; ++r) {
                    v0[r] = fmaf(c[l], s[10 * l + r],     v0[r]);
                    t[r]  = fmaf(c[l], s[10 * l + 5 + r], t[r]);
                }
#pragma unroll
            for (int r = 0; r < 5; ++r) c[r] = fmaf(xv, t[r], v0[r]);
            xv = xn;
        }
        __syncthreads();   // b1: phase-1 matrices (waves 1..7) ready
        // c <- c @ P_w for w = 1..7
#pragma unroll 1
        for (int w = 0; w < 7; ++w) {
            float v0[5];
#pragma unroll
            for (int r = 0; r < 5; ++r) v0[r] = c[0] * matbuf[w][r][lane];
#pragma unroll
            for (int l = 1; l < 5; ++l)
#pragma unroll
                for (int r = 0; r < 5; ++r)
                    v0[r] = fmaf(c[l], matbuf[w][l * 5 + r][lane], v0[r]);
#pragma unroll
            for (int r = 0; r < 5; ++r) c[r] = v0[r];
        }
        __syncthreads();   // b2: done reading phase 1, writers may overwrite
        __syncthreads();   // b3: phase-2 matrices (waves 8..14) + bv ready
#pragma unroll 1
        for (int w = 0; w < 7; ++w) {
            float v0[5];
#pragma unroll
            for (int r = 0; r < 5; ++r) v0[r] = c[0] * matbuf[w][r][lane];
#pragma unroll
            for (int l = 1; l < 5; ++l)
#pragma unroll
                for (int r = 0; r < 5; ++r)
                    v0[r] = fmaf(c[l], matbuf[w][l * 5 + r][lane], v0[r]);
#pragma unroll
            for (int r = 0; r < 5; ++r) c[r] = v0[r];
        }
        float res = 0.0f;
#pragma unroll
        for (int l = 0; l < 5; ++l) res = fmaf(c[l], bv[l][lane], res);
        float* orow = out + (size_t)row * NOUT;
#pragma unroll
        for (int o = 0; o < NOUT; ++o) orow[o] = fmaf(res, fc_w[o], fc_b[o]);
    } else if (wave == 15) {
        // ---- backward vector segment: d=783 init, then m = 781..671 ----
        float c[5];
        const float xl = xr[Dn - 1];
#pragma unroll
        for (int l = 0; l < 5; ++l)
            c[l] = fmaf(xl, core_last[2 * l + 1] - core_last[2 * l], core_last[2 * l]);
        float xv = xr[NMID];                       // d = 782 for m = 781
        for (int m = NMID - 1; m >= NMID - NVEC; --m) {
            const float* s = pk + (size_t)m * PKW;
            const float xn = xr[m];                // next site (m-1) uses x[d=m]
            float v0[5], t[5];
#pragma unroll
            for (int l = 0; l < 5; ++l) { v0[l] = s[10 * l] * c[0]; t[l] = s[10 * l + 5] * c[0]; }
#pragma unroll
            for (int r = 1; r < 5; ++r)
#pragma unroll
                for (int l = 0; l < 5; ++l) {
                    v0[l] = fmaf(s[10 * l + r],     c[r], v0[l]);
                    t[l]  = fmaf(s[10 * l + 5 + r], c[r], t[l]);
                }
#pragma unroll
            for (int l = 0; l < 5; ++l) c[l] = fmaf(xv, t[l], v0[l]);
            xv = xn;
        }
        __syncthreads();   // b1
        __syncthreads();   // b2
#pragma unroll
        for (int l = 0; l < 5; ++l) bv[l][lane] = c[l];
        __syncthreads();   // b3
    } else {
        // ---- matrix segment wave w = 1..14: m in [m0, m0+NMAT) ----
        const int w  = wave;
        const int m0 = NVEC + (w - 1) * NMAT;
        float M[25], T[25];
#pragma unroll
        for (int k = 0; k < 25; ++k) M[k] = (k % 6 == 0) ? 1.0f : 0.0f;  // identity
        float xv = xr[m0 + 1];
        for (int s2 = 0; s2 < NMAT; s2 += 2) {
            const float* sa = pk + (size_t)(m0 + s2) * PKW;
            float xn = xr[m0 + s2 + 2];
            mstep(M, T, sa, xv);
            xv = xn;
            const float* sb = sa + PKW;
            xn = xr[m0 + s2 + 3];                  // max read: xr[672], in bounds
            mstep(T, M, sb, xv);
            xv = xn;
        }
        if (w <= 7) {
#pragma unroll
            for (int k = 0; k < 25; ++k) matbuf[w - 1][k][lane] = M[k];
        }
        __syncthreads();   // b1
        __syncthreads();   // b2
        if (w >= 8) {
#pragma unroll
            for (int k = 0; k < 25; ++k) matbuf[w - 8][k][lane] = M[k];
        }
        __syncthreads();   // b3
    }
}

extern "C" void kernel_launch(void* const* d_in, const int* in_sizes, int n_in,
                              void* d_out, int out_size, void* d_ws, size_t ws_size,
                              hipStream_t stream) {
    const float* x          = (const float*)d_in[0];
    const float* core_first = (const float*)d_in[1];
    const float* cores_mid  = (const float*)d_in[2];
    const float* core_last  = (const float*)d_in[3];
    const float* fc_w       = (const float*)d_in[4];
    const float* fc_b       = (const float*)d_in[5];
    float* out              = (float*)d_out;
    float* pk               = (float*)d_ws;        // needs 782*64*4 = 200,192 B

    // prepack cores as [A0 | A1-A0] per site, padded to 64 floats (256 B)
    hipLaunchKernelGGL(prepack_kernel, dim3((NMID * 50 + 255) / 256), dim3(256),
                       0, stream, cores_mid, pk);

    hipLaunchKernelGGL(mps_seg_kernel, dim3(Bn / 64), dim3(1024), 0, stream,
                       x, core_first, core_last, fc_w, fc_b, pk, out);
}

// Round 3
// 126.117 us; speedup vs baseline: 1.9777x; 1.3777x over previous
//
#include <hip/hip_runtime.h>

// MPS tensor-train classifier, B=16384, D=784, BOND=5, OUT=10.
//
// res[b] = carry0(x0) . (prod_{m=0..781} M_m(x[m+1])) . vlast(x783)
// Round-3: SITE-PAIRING. For pair p (sites m=2p+1, 2p+2):
//   C_p = M_{2p+1} M_{2p+2} = P0 + xa*P1 + xb*P2 + xa*xb*P3
// with P0=A0A0', P1=NA0', P2=A0N', P3=NN' precomputed (prepack kernel).
// Halves matrix-chain VALU. Singles: site 0 (fwd wave) and site 781 (bwd).
// Pairs >= BWD_P0 are stored TRANSPOSED so the bwd wave uses identical
// row-vector code (v' = v @ C^T == (C v)^T).
//
// 256 blocks x 1024 thr (16 waves), lane = batch row. Wave 0: fwd vector
// chain (site 0 + pairs 0..40). Waves 1..14: 22-pair matrix products.
// Wave 15: bwd (pairs 389..349 desc + site 781). Combine via LDS (2 phases).
// pk staged through LDS double-buffer (4-pair chunks); x via v2f prefetch
// ring. Packed fp32 (ext_vector_type) for v_pk_fma_f32 selection.

typedef float v4f __attribute__((ext_vector_type(4)));
typedef float v2f __attribute__((ext_vector_type(2)));

constexpr int Bn     = 16384;
constexpr int Dn     = 784;
constexpr int NOUT   = 10;
constexpr int NPAIR  = 390;   // pairs cover sites 1..780
constexpr int PFV    = 41;    // fwd pairs 0..40
constexpr int PMAT   = 22;    // pairs per matrix wave (14 waves: 41..348)
constexpr int BWD_P0 = 349;   // bwd pairs 349..389 (stored transposed)
constexpr int PAIR_F = 112;   // floats per pair block: 4 mats x 28
// per-mat layout (28 floats): rows cols0-3 at 4*l (l=0..4), col4 of rows0-3
// at 20..23, element (4,4) at 24, pad 25..27.

__device__ __forceinline__ v4f splat4(float x) { v4f v = {x, x, x, x}; return v; }
__device__ __forceinline__ v4f fma4(v4f a, v4f b, v4f c) {
    return __builtin_elementwise_fma(a, b, c);
}

struct Frag { v4f r[5]; float c4[5]; };          // 5x5 running product
struct CMat { v4f row[5]; v4f c4v; float c44; }; // 5x5 pair matrix

__device__ __forceinline__ CMat build_C(const float* s, float xa, float xb) {
    CMat C;
    const float xab = xa * xb;
    const v4f va = splat4(xa), vb = splat4(xb), vab = splat4(xab);
    const v4f* s4 = (const v4f*)s;
#pragma unroll
    for (int l = 0; l < 5; ++l) {
        v4f m = s4[l];
        m = fma4(va,  s4[7 + l],  m);
        m = fma4(vb,  s4[14 + l], m);
        m = fma4(vab, s4[21 + l], m);
        C.row[l] = m;
    }
    {
        v4f m = s4[5];
        m = fma4(va,  s4[12], m);
        m = fma4(vb,  s4[19], m);
        m = fma4(vab, s4[26], m);
        C.c4v = m;
    }
    C.c44 = fmaf(xab, s[108], fmaf(xb, s[80], fmaf(xa, s[52], s[24])));
    return C;
}

// T = M @ C
__device__ __forceinline__ void matmul(const Frag& M, const CMat& C, Frag& T) {
#pragma unroll
    for (int i = 0; i < 5; ++i) {
        v4f acc  = splat4(M.r[i][0]) * C.row[0];
        float a4 = M.r[i][0] * C.c4v[0];
#pragma unroll
        for (int l = 1; l < 4; ++l) {
            acc = fma4(splat4(M.r[i][l]), C.row[l], acc);
            a4  = fmaf(M.r[i][l], C.c4v[l], a4);
        }
        acc = fma4(splat4(M.c4[i]), C.row[4], acc);
        a4  = fmaf(M.c4[i], C.c44, a4);
        T.r[i] = acc; T.c4[i] = a4;
    }
}

// c' = c @ C   (row vector)
__device__ __forceinline__ void vecstep(v4f& cv, float& c4, const CMat& C) {
    v4f acc  = splat4(cv[0]) * C.row[0];
    float a4 = cv[0] * C.c4v[0];
#pragma unroll
    for (int l = 1; l < 4; ++l) {
        acc = fma4(splat4(cv[l]), C.row[l], acc);
        a4  = fmaf(cv[l], C.c4v[l], a4);
    }
    acc = fma4(splat4(c4), C.row[4], acc);
    a4  = fmaf(c4, C.c44, a4);
    cv = acc; c4 = a4;
}

// staging: one chunk = 4 pair blocks = 112 v4f = 1792 B
__device__ __forceinline__ void sload(const v4f* src, v4f& a, v4f& b, int lane) {
    a = src[lane];
    if (lane < 48) b = src[64 + lane];
}
__device__ __forceinline__ void swrite(v4f* dst, v4f a, v4f b, int lane) {
    dst[lane] = a;
    if (lane < 48) dst[64 + lane] = b;
}

// ---- prepack: build pair blocks (transposed for p >= BWD_P0) ----
// cores_mid element (m,l,i,k) at (m*5+l)*10 + i*5 + k
__global__ void prepack_pairs(const float* __restrict__ cm, float* __restrict__ pk)
{
    int idx = blockIdx.x * 256 + threadIdx.x;
    if (idx >= NPAIR * 100) return;
    int p = idx / 100, rest = idx - p * 100;
    int q = rest / 25, e = rest - q * 25;
    int l = e / 5, r = e - l * 5;
    int m1 = 2 * p + 1, m2 = 2 * p + 2;
    const float* L = cm + (size_t)(m1 * 5 + l) * 10;
    float acc = 0.f;
#pragma unroll
    for (int k = 0; k < 5; ++k) {
        float Lk = (q & 1) ? (L[5 + k] - L[k]) : L[k];
        const float* R = cm + (size_t)(m2 * 5 + k) * 10;
        float Rk = (q & 2) ? (R[5 + r] - R[r]) : R[r];
        acc = fmaf(Lk, Rk, acc);
    }
    int wl = l, wr = r;
    if (p >= BWD_P0) { wl = r; wr = l; }   // store C^T for bwd wave
    int off = (wr < 4) ? (wl * 4 + wr) : (20 + wl);
    pk[(size_t)p * PAIR_F + q * 28 + off] = acc;
}

__global__ __launch_bounds__(1024)
void mps_pair_kernel(const float* __restrict__ x,          // [B, D]
                     const float* __restrict__ core_first, // [2,5]
                     const float* __restrict__ cores_mid,  // [782,5,2,5]
                     const float* __restrict__ core_last,  // [5,2]
                     const float* __restrict__ fc_w,       // [10]
                     const float* __restrict__ fc_b,       // [10]
                     const float* __restrict__ pk,         // [390][112]
                     float* __restrict__ out)              // [B,10]
{
    __shared__ v4f   pkbuf[16][2][112];   // 57.3 KB double-buffered pair chunks
    __shared__ float matbuf[7][25][64];   // 44.8 KB combine matrices
    __shared__ float bv[5][64];           // backward vectors

    const int lane = threadIdx.x & 63;
    const int wave = threadIdx.x >> 6;
    const int row  = blockIdx.x * 64 + lane;
    const float* __restrict__ xr = x + (size_t)row * Dn;
    const v2f* __restrict__ xr2 = (const v2f*)xr;          // 392 entries
    const v4f* __restrict__ pk4 = (const v4f*)pk;

    v4f* buf0 = &pkbuf[wave][0][0];
    v4f* buf1 = &pkbuf[wave][1][0];

    if (wave >= 1 && wave <= 14) {
        // ---- matrix wave: 22 pairs, 6 chunks (5x4 + 1x2) ----
        const int w  = wave;
        const int p0 = PFV + PMAT * (w - 1);
        v4f sa, sb;
        sload(pk4 + (size_t)p0 * 28, sa, sb, lane);
        swrite(buf0, sa, sb, lane);
        sload(pk4 + (size_t)(p0 + 4) * 28, sa, sb, lane);
        v2f xc0 = xr2[p0 + 1], xc1 = xr2[p0 + 2], xc2 = xr2[p0 + 3], xc3 = xr2[p0 + 4];

        Frag M, T;
        M.r[0] = {1,0,0,0}; M.r[1] = {0,1,0,0}; M.r[2] = {0,0,1,0};
        M.r[3] = {0,0,0,1}; M.r[4] = {0,0,0,0};
        M.c4[0] = 0; M.c4[1] = 0; M.c4[2] = 0; M.c4[3] = 0; M.c4[4] = 1;

#pragma unroll 1
        for (int c = 0; c < 6; ++c) {
            v4f* wb = (c & 1) ? buf0 : buf1;
            const float* rb = (const float*)((c & 1) ? buf1 : buf0);
            swrite(wb, sa, sb, lane);                      // chunk c+1 -> LDS
            int ns = p0 + 4 * (c + 2);                     // next-next chunk
            if (ns > NPAIR - 4) ns = NPAIR - 4;
            sload(pk4 + (size_t)ns * 28, sa, sb, lane);
            const int pn = p0 + 4 * (c + 1);               // x prefetch
            v2f xn0 = xr2[pn + 1], xn1 = xr2[pn + 2], xn2 = xr2[pn + 3], xn3 = xr2[pn + 4];
            {
                CMat C = build_C(rb + 0 * PAIR_F, xc0[0], xc0[1]);
                matmul(M, C, T);
                C = build_C(rb + 1 * PAIR_F, xc1[0], xc1[1]);
                matmul(T, C, M);
            }
            if (c < 5) {
                CMat C = build_C(rb + 2 * PAIR_F, xc2[0], xc2[1]);
                matmul(M, C, T);
                C = build_C(rb + 3 * PAIR_F, xc3[0], xc3[1]);
                matmul(T, C, M);
            }
            xc0 = xn0; xc1 = xn1; xc2 = xn2; xc3 = xn3;
        }

        if (w <= 7) {
#pragma unroll
            for (int i = 0; i < 5; ++i) {
#pragma unroll
                for (int r = 0; r < 4; ++r) matbuf[w - 1][i * 5 + r][lane] = M.r[i][r];
                matbuf[w - 1][i * 5 + 4][lane] = M.c4[i];
            }
        }
        __syncthreads();   // b1
        __syncthreads();   // b2
        if (w >= 8) {
#pragma unroll
            for (int i = 0; i < 5; ++i) {
#pragma unroll
                for (int r = 0; r < 4; ++r) matbuf[w - 8][i * 5 + r][lane] = M.r[i][r];
                matbuf[w - 8][i * 5 + 4][lane] = M.c4[i];
            }
        }
        __syncthreads();   // b3
    } else if (wave == 0) {
        // ---- forward: carry0, site 0 (scalar), pairs 0..40, combine ----
        v2f x01 = xr2[0];
        float cl[5], cn[5];
#pragma unroll
        for (int r = 0; r < 5; ++r)
            cl[r] = fmaf(x01[0], core_first[5 + r] - core_first[r], core_first[r]);
        const float* cm0 = cores_mid;                      // site 0
#pragma unroll
        for (int r = 0; r < 5; ++r) {
            float a = 0.f;
#pragma unroll
            for (int l = 0; l < 5; ++l) {
                float m = fmaf(x01[1], cm0[l * 10 + 5 + r] - cm0[l * 10 + r], cm0[l * 10 + r]);
                a = fmaf(cl[l], m, a);
            }
            cn[r] = a;
        }
        v4f cv = {cn[0], cn[1], cn[2], cn[3]};
        float c4 = cn[4];

        v4f sa, sb;
        sload(pk4 + 0, sa, sb, lane);
        swrite(buf0, sa, sb, lane);
        sload(pk4 + (size_t)4 * 28, sa, sb, lane);
        v2f xc0 = xr2[1], xc1 = xr2[2], xc2 = xr2[3], xc3 = xr2[4];

#pragma unroll 1
        for (int c = 0; c < 11; ++c) {                     // 10x4 + 1x1 = 41 pairs
            v4f* wb = (c & 1) ? buf0 : buf1;
            const float* rb = (const float*)((c & 1) ? buf1 : buf0);
            swrite(wb, sa, sb, lane);
            int ns = 4 * (c + 2);
            if (ns > NPAIR - 4) ns = NPAIR - 4;
            sload(pk4 + (size_t)ns * 28, sa, sb, lane);
            const int pn = 4 * (c + 1);
            v2f xn0 = xr2[pn + 1], xn1 = xr2[pn + 2], xn2 = xr2[pn + 3], xn3 = xr2[pn + 4];
            {
                CMat C = build_C(rb + 0 * PAIR_F, xc0[0], xc0[1]);
                vecstep(cv, c4, C);
            }
            if (c < 10) {
                CMat C = build_C(rb + 1 * PAIR_F, xc1[0], xc1[1]);
                vecstep(cv, c4, C);
                C = build_C(rb + 2 * PAIR_F, xc2[0], xc2[1]);
                vecstep(cv, c4, C);
                C = build_C(rb + 3 * PAIR_F, xc3[0], xc3[1]);
                vecstep(cv, c4, C);
            }
            xc0 = xn0; xc1 = xn1; xc2 = xn2; xc3 = xn3;
        }
        cl[0] = cv[0]; cl[1] = cv[1]; cl[2] = cv[2]; cl[3] = cv[3]; cl[4] = c4;

        __syncthreads();   // b1: phase-1 matrices ready
#pragma unroll 1
        for (int w2 = 0; w2 < 7; ++w2) {
            float v0[5];
#pragma unroll
            for (int r = 0; r < 5; ++r) v0[r] = cl[0] * matbuf[w2][r][lane];
#pragma unroll
            for (int l = 1; l < 5; ++l)
#pragma unroll
                for (int r = 0; r < 5; ++r)
                    v0[r] = fmaf(cl[l], matbuf[w2][l * 5 + r][lane], v0[r]);
#pragma unroll
            for (int r = 0; r < 5; ++r) cl[r] = v0[r];
        }
        __syncthreads();   // b2
        __syncthreads();   // b3: phase-2 matrices + bv ready
#pragma unroll 1
        for (int w2 = 0; w2 < 7; ++w2) {
            float v0[5];
#pragma unroll
            for (int r = 0; r < 5; ++r) v0[r] = cl[0] * matbuf[w2][r][lane];
#pragma unroll
            for (int l = 1; l < 5; ++l)
#pragma unroll
                for (int r = 0; r < 5; ++r)
                    v0[r] = fmaf(cl[l], matbuf[w2][l * 5 + r][lane], v0[r]);
#pragma unroll
            for (int r = 0; r < 5; ++r) cl[r] = v0[r];
        }
        float res = 0.f;
#pragma unroll
        for (int l = 0; l < 5; ++l) res = fmaf(cl[l], bv[l][lane], res);
        float* orow = out + (size_t)row * NOUT;
#pragma unroll
        for (int o = 0; o < NOUT; ++o) orow[o] = fmaf(res, fc_w[o], fc_b[o]);
    } else {
        // ---- backward: vlast, site 781 (scalar), pairs 389..349 desc ----
        v2f xz = xr2[391];                                 // {x782, x783}
        float vl[5], vn[5];
#pragma unroll
        for (int l = 0; l < 5; ++l)
            vl[l] = fmaf(xz[1], core_last[2 * l + 1] - core_last[2 * l], core_last[2 * l]);
        const float* cmL = cores_mid + (size_t)781 * 50;
#pragma unroll
        for (int l = 0; l < 5; ++l) {
            float a = 0.f;
#pragma unroll
            for (int r = 0; r < 5; ++r) {
                float m = fmaf(xz[0], cmL[l * 10 + 5 + r] - cmL[l * 10 + r], cmL[l * 10 + r]);
                a = fmaf(m, vl[r], a);
            }
            vn[l] = a;
        }
        v4f cv = {vn[0], vn[1], vn[2], vn[3]};
        float c4 = vn[4];

        v4f sa, sb;
        sload(pk4 + (size_t)386 * 28, sa, sb, lane);       // chunk0: pairs 386..389
        swrite(buf0, sa, sb, lane);
        sload(pk4 + (size_t)382 * 28, sa, sb, lane);
        v2f xc0 = xr2[390], xc1 = xr2[389], xc2 = xr2[388], xc3 = xr2[387];

#pragma unroll 1
        for (int c = 0; c < 11; ++c) {                     // 10x4 + 1x1 = 41 pairs
            v4f* wb = (c & 1) ? buf0 : buf1;
            const float* rb = (const float*)((c & 1) ? buf1 : buf0);
            swrite(wb, sa, sb, lane);
            int ns = 386 - 4 * (c + 2);                    // >= 338, in bounds
            sload(pk4 + (size_t)ns * 28, sa, sb, lane);
            const int bn = 386 - 4 * (c + 1);
            v2f xn0 = xr2[bn + 4], xn1 = xr2[bn + 3], xn2 = xr2[bn + 2], xn3 = xr2[bn + 1];
            {
                CMat C = build_C(rb + 3 * PAIR_F, xc0[0], xc0[1]);  // highest pair first
                vecstep(cv, c4, C);
            }
            if (c < 10) {
                CMat C = build_C(rb + 2 * PAIR_F, xc1[0], xc1[1]);
                vecstep(cv, c4, C);
                C = build_C(rb + 1 * PAIR_F, xc2[0], xc2[1]);
                vecstep(cv, c4, C);
                C = build_C(rb + 0 * PAIR_F, xc3[0], xc3[1]);
                vecstep(cv, c4, C);
            }
            xc0 = xn0; xc1 = xn1; xc2 = xn2; xc3 = xn3;
        }

        __syncthreads();   // b1
        __syncthreads();   // b2
        bv[0][lane] = cv[0]; bv[1][lane] = cv[1]; bv[2][lane] = cv[2];
        bv[3][lane] = cv[3]; bv[4][lane] = c4;
        __syncthreads();   // b3
    }
}

extern "C" void kernel_launch(void* const* d_in, const int* in_sizes, int n_in,
                              void* d_out, int out_size, void* d_ws, size_t ws_size,
                              hipStream_t stream) {
    const float* x          = (const float*)d_in[0];
    const float* core_first = (const float*)d_in[1];
    const float* cores_mid  = (const float*)d_in[2];
    const float* core_last  = (const float*)d_in[3];
    const float* fc_w       = (const float*)d_in[4];
    const float* fc_b       = (const float*)d_in[5];
    float* out              = (float*)d_out;
    float* pk               = (float*)d_ws;   // 390*112*4 = 174,720 B

    hipLaunchKernelGGL(prepack_pairs, dim3((NPAIR * 100 + 255) / 256), dim3(256),
                       0, stream, cores_mid, pk);
    hipLaunchKernelGGL(mps_pair_kernel, dim3(Bn / 64), dim3(1024), 0, stream,
                       x, core_first, cores_mid, core_last, fc_w, fc_b, pk, out);
}